// Round 2
// baseline (924.280 us; speedup 1.0000x reference)
//
#include <hip/hip_runtime.h>
#include <hip/hip_bf16.h>
#include <stdint.h>

typedef __hip_bfloat16 bf16;

#define BVOXN 23328   // B * 729, B = 32 (fixed by setup_inputs)

__device__ __forceinline__ float b2f(bf16 v) { return __bfloat162float(v); }

// ---- workspace layout (float offsets) -------------------------------------
#define OFF_L0W   64        // 192   lin0_w f32
#define OFF_B0    256       // 64    lin0_b
#define OFF_W0    320       // 5184  conv0_w
#define OFF_CB0   5504      // 64    conv0_b
#define OFF_L1W   5568      // 4096  lin1_w
#define OFF_B1    9664      // 64    lin1_b
#define OFF_W1T   9728      // 110592 conv1_w transposed [i][tap][o]
#define OFF_CB1   120320    // 64    conv1_b
#define OFF_LFW   120384    // 192   linf_w
#define OFF_BF    120576    // 64    linf_b
#define OFF_SUMS  120640    // 93312  per-cluster sums+count (zeroed)
#define OFF_GA0   213952    // 69984  conv0 input grid (zeroed)
#define OFF_GA1   283936    // 1492992 conv1 input grid (zeroed)
#define OFF_C1O   1776928   // 1492992 conv1 out, atomic target (zeroed)
#define OFF_C0O   3269920   // 1492992 conv0 out
#define OFF_WC    4762912   // 192   folded point matrix
#define OFF_BVEC  4763104   // 64    folded bias
#define OFF_G     4763168   // 1492992 bf16 voxel table G

// ---------------------------------------------------------------------------
// Decide whether float inputs are f32 (flag=1) or bf16 (flag=0).
// bf16 view of an f32 buffer: even elements = low mantissa bits -> random
// exponents -> mostly huge/tiny/NaN. bf16 view of real bf16 weights: sane.
__global__ void k_probe(const void* lin1_w, int* flag) {
    __shared__ int cnt[256];
    int t = threadIdx.x;
    const bf16* p = (const bf16*)lin1_w;
    int c = 0;
    for (int j = t; j < 2048; j += 256) {
        float v = b2f(p[2 * j]);
        if (!(v == v) || fabsf(v) > 64.0f || (v != 0.0f && fabsf(v) < 1e-20f)) c++;
    }
    cnt[t] = c;
    __syncthreads();
    for (int s = 128; s > 0; s >>= 1) {
        if (t < s) cnt[t] += cnt[t + s];
        __syncthreads();
    }
    if (t == 0) *flag = (cnt[0] > 100) ? 1 : 0;
}

__device__ __forceinline__ float ldf(const void* p, int j, int isf) {
    return isf ? ((const float*)p)[j] : b2f(((const bf16*)p)[j]);
}

// Convert all 10 weight arrays into canonical f32 ws copies (conv1_w transposed).
__global__ void k_convert(const void* l0w, const void* l0b, const void* w0,
                          const void* cb0, const void* l1w, const void* l1b,
                          const void* w1, const void* cb1, const void* lfw,
                          const void* lfb, const int* flag, float* ws) {
    int t = blockIdx.x * 256 + threadIdx.x;
    if (t >= 120576) return;
    int isf = *flag;
    const void* src;
    int j;
    float* dst;
    if (t < 192)        { src = l0w; j = t;          dst = ws + OFF_L0W + j; }
    else if (t < 256)   { src = l0b; j = t - 192;    dst = ws + OFF_B0  + j; }
    else if (t < 5440)  { src = w0;  j = t - 256;    dst = ws + OFF_W0  + j; }
    else if (t < 5504)  { src = cb0; j = t - 5440;   dst = ws + OFF_CB0 + j; }
    else if (t < 9600)  { src = l1w; j = t - 5504;   dst = ws + OFF_L1W + j; }
    else if (t < 9664)  { src = l1b; j = t - 9600;   dst = ws + OFF_B1  + j; }
    else if (t < 120256) {
        j = t - 9664;                       // source index into conv1_w [o][i][tap]
        int o = j / 1728, r = j % 1728, i = r / 27, tap = r % 27;
        src = w1;
        dst = ws + OFF_W1T + (i * 27 + tap) * 64 + o;
    }
    else if (t < 120320) { src = cb1; j = t - 120256; dst = ws + OFF_CB1 + j; }
    else if (t < 120512) { src = lfw; j = t - 120320; dst = ws + OFF_LFW + j; }
    else                 { src = lfb; j = t - 120512; dst = ws + OFF_BF  + j; }
    *dst = ldf(src, j, isf);
}

// Fold: Wc = lin0_w@lin1_w + linf_w [3,64]; bvec = lin0_b@lin1_w + lin1_b + linf_b
__global__ void k_prep(const float* ws, float* Wc, float* bvec) {
    const float* l0w = ws + OFF_L0W;
    const float* l0b = ws + OFF_B0;
    const float* l1w = ws + OFF_L1W;
    const float* l1b = ws + OFF_B1;
    const float* lfw = ws + OFF_LFW;
    const float* lfb = ws + OFF_BF;
    int c = threadIdx.x;
    float bv = l1b[c] + lfb[c];
    for (int k = 0; k < 64; ++k) bv += l0b[k] * l1w[k * 64 + c];
    bvec[c] = bv;
    for (int r = 0; r < 3; ++r) {
        float wv = lfw[r * 64 + c];
        for (int k = 0; k < 64; ++k) wv += l0w[r * 64 + k] * l1w[k * 64 + c];
        Wc[r * 64 + c] = wv;
    }
}

// Per-cluster sums of x (3 ch) + counts via f32 atomics.
__global__ void k_accum(const void* x, const int* consec, const int* flag,
                        float* sums4, int N) {
    int i = blockIdx.x * 256 + threadIdx.x;
    if (i >= N) return;
    int isf = *flag;
    int u = consec[i];
    atomicAdd(&sums4[u * 4 + 0], ldf(x, 3 * i + 0, isf));
    atomicAdd(&sums4[u * 4 + 1], ldf(x, 3 * i + 1, isf));
    atomicAdd(&sums4[u * 4 + 2], ldf(x, 3 * i + 2, isf));
    atomicAdd(&sums4[u * 4 + 3], 1.0f);
}

// Scatter means into conv0 input grid (flat [3, BVOXN] raw-viewed as (B,3,9,9,9))
__global__ void k_scatter0(const float* sums4, const int* unc, float* gridA0, int U) {
    int u = blockIdx.x * 256 + threadIdx.x;
    if (u >= U) return;
    int v = unc[u];
    float inv = 1.0f / sums4[u * 4 + 3];
    gridA0[0 * BVOXN + v] = sums4[u * 4 + 0] * inv;
    gridA0[1 * BVOXN + v] = sums4[u * 4 + 1] * inv;
    gridA0[2 * BVOXN + v] = sums4[u * 4 + 2] * inv;
}

// conv0: (B,3,9,9,9) -> (B,64,9,9,9), 3x3x3, pad 1, + bias.
__global__ void k_conv0(const float* gridA0, const float* w0, const float* cb0,
                        float* conv0o) {
    int idx = blockIdx.x * 256 + threadIdx.x;
    if (idx >= 64 * BVOXN) return;
    int b = idx / 46656;
    int r = idx % 46656;
    int o = r / 729;
    int dhw = r % 729;
    int d = dhw / 81, h = (dhw / 9) % 9, w = dhw % 9;
    float acc = cb0[o];
    const float* gb = gridA0 + b * 2187;
    const float* wb = w0 + o * 81;
    for (int ci = 0; ci < 3; ++ci)
        for (int kd = 0; kd < 3; ++kd) {
            int z = d + kd - 1;
            if ((unsigned)z >= 9u) continue;
            for (int kh = 0; kh < 3; ++kh) {
                int hh = h + kh - 1;
                if ((unsigned)hh >= 9u) continue;
                #pragma unroll
                for (int kw = 0; kw < 3; ++kw) {
                    int ww = w + kw - 1;
                    if ((unsigned)ww >= 9u) continue;
                    acc += gb[ci * 729 + z * 81 + hh * 9 + ww] *
                           wb[ci * 27 + kd * 9 + kh * 3 + kw];
                }
            }
        }
    conv0o[idx] = acc;
}

// conv1 input grid: gridA1(c,v) = mean_x[u]@lin0_w[:,c] + lin0_b[c] + conv0o(c,v)
__global__ void k_scatter1(const float* sums4, const int* unc, const float* conv0o,
                           const float* l0w, const float* l0b, float* gridA1) {
    int u = blockIdx.x;
    int c = threadIdx.x;
    int v = unc[u];
    float inv = 1.0f / sums4[u * 4 + 3];
    float m0 = sums4[u * 4 + 0] * inv;
    float m1 = sums4[u * 4 + 1] * inv;
    float m2 = sums4[u * 4 + 2] * inv;
    gridA1[c * BVOXN + v] = l0b[c] + m0 * l0w[c] + m1 * l0w[64 + c] +
                            m2 * l0w[128 + c] + conv0o[c * BVOXN + v];
}

// conv1: (B,64,9,9,9)->(B,64,9,9,9), 3x3x3 pad 1. Block=(b, d-plane, i-half).
// LDS: zero-padded 11x11 planes, 32 in-ch x 3 z. Thread: 8 o x 3 hw register tile.
// Partials combined via atomicAdd (bias added in k_G).
__global__ __launch_bounds__(256) void k_conv1(const float* gridA1, const float* w1t,
                                               float* conv1o) {
    __shared__ float slab[32 * 363];
    int blk = blockIdx.x;
    int ih = blk & 1;
    int t2 = blk >> 1;
    int b = t2 / 9, d = t2 % 9;
    int t = threadIdx.x;

    for (int s = t; s < 32 * 363; s += 256) {
        int i = s / 363, rr = s % 363;
        int zz = rr / 121, p = rr % 121;
        int ph = p / 11, pw = p % 11;
        int z = d + zz - 1, hh = ph - 1, ww = pw - 1;
        float v = 0.0f;
        if ((unsigned)z < 9u && (unsigned)hh < 9u && (unsigned)ww < 9u)
            v = gridA1[b * 46656 + (ih * 32 + i) * 729 + z * 81 + hh * 9 + ww];
        slab[s] = v;
    }
    __syncthreads();

    int og = t >> 5, l = t & 31;
    int hw[3], hj[3], wj[3];
    bool valid[3];
    #pragma unroll
    for (int j = 0; j < 3; ++j) {
        int q = l + 32 * j;
        valid[j] = q < 81;
        int qc = q < 81 ? q : 80;
        hw[j] = q;
        hj[j] = qc / 9;
        wj[j] = qc % 9;
    }
    float acc[8][3];
    #pragma unroll
    for (int a = 0; a < 8; ++a)
        #pragma unroll
        for (int j = 0; j < 3; ++j) acc[a][j] = 0.0f;

    for (int i = 0; i < 32; ++i) {
        const float* sb = slab + i * 363;
        const float* wb = w1t + ((ih * 32 + i) * 27) * 64 + og * 8;
        for (int kd = 0; kd < 3; ++kd)
            for (int kh = 0; kh < 3; ++kh) {
                int ib0 = kd * 121 + (hj[0] + kh) * 11 + wj[0];
                int ib1 = kd * 121 + (hj[1] + kh) * 11 + wj[1];
                int ib2 = kd * 121 + (hj[2] + kh) * 11 + wj[2];
                #pragma unroll
                for (int kw = 0; kw < 3; ++kw) {
                    int tap = kd * 9 + kh * 3 + kw;
                    const float4* w4 = reinterpret_cast<const float4*>(wb + tap * 64);
                    float4 wA = w4[0];
                    float4 wB = w4[1];
                    float in0 = sb[ib0 + kw];
                    float in1 = sb[ib1 + kw];
                    float in2 = sb[ib2 + kw];
                    acc[0][0] += wA.x * in0; acc[0][1] += wA.x * in1; acc[0][2] += wA.x * in2;
                    acc[1][0] += wA.y * in0; acc[1][1] += wA.y * in1; acc[1][2] += wA.y * in2;
                    acc[2][0] += wA.z * in0; acc[2][1] += wA.z * in1; acc[2][2] += wA.z * in2;
                    acc[3][0] += wA.w * in0; acc[3][1] += wA.w * in1; acc[3][2] += wA.w * in2;
                    acc[4][0] += wB.x * in0; acc[4][1] += wB.x * in1; acc[4][2] += wB.x * in2;
                    acc[5][0] += wB.y * in0; acc[5][1] += wB.y * in1; acc[5][2] += wB.y * in2;
                    acc[6][0] += wB.z * in0; acc[6][1] += wB.z * in1; acc[6][2] += wB.z * in2;
                    acc[7][0] += wB.w * in0; acc[7][1] += wB.w * in1; acc[7][2] += wB.w * in2;
                }
            }
    }

    #pragma unroll
    for (int oj = 0; oj < 8; ++oj) {
        int o = og * 8 + oj;
        #pragma unroll
        for (int j = 0; j < 3; ++j)
            if (valid[j])
                atomicAdd(&conv1o[b * 46656 + o * 729 + d * 81 + hw[j]], acc[oj][j]);
    }
}

// G(v,c) = sum_k conv0o(k,v)*lin1_w[k][c] + conv1o(c,v) + conv1_b[o(p)]
__global__ void k_G(const float* conv0o, const float* conv1o, const float* l1w,
                    const float* cb1, bf16* G) {
    int v = blockIdx.x;
    int c = threadIdx.x;
    float a = 0.0f;
    for (int k = 0; k < 64; ++k)
        a += conv0o[k * BVOXN + v] * l1w[k * 64 + c];
    int p = c * BVOXN + v;
    a += conv1o[p] + cb1[(p / 729) & 63];
    G[v * 64 + c] = __float2bfloat16(a);
}

// out[i][c] = x[i]@Wc[:,c] + bvec[c] + G[cnc[i]][c]
__global__ __launch_bounds__(256) void k_out(const void* x, const int* cnc,
                                             const float* Wc, const float* bvec,
                                             const bf16* G, const int* flag,
                                             void* out, int N) {
    int t = blockIdx.x * 256 + threadIdx.x;
    int i = t >> 6;
    int c = t & 63;
    if (i >= N) return;
    int isf = *flag;
    int v = cnc[i];
    float x0 = ldf(x, 3 * i + 0, isf);
    float x1 = ldf(x, 3 * i + 1, isf);
    float x2 = ldf(x, 3 * i + 2, isf);
    float r = bvec[c] + x0 * Wc[c] + x1 * Wc[64 + c] + x2 * Wc[128 + c] +
              b2f(G[v * 64 + c]);
    size_t oi = (size_t)i * 64 + c;
    if (isf) ((float*)out)[oi] = r;
    else ((bf16*)out)[oi] = __float2bfloat16(r);
}

// ---------------------------------------------------------------------------
extern "C" void kernel_launch(void* const* d_in, const int* in_sizes, int n_in,
                              void* d_out, int out_size, void* d_ws, size_t ws_size,
                              hipStream_t stream) {
    const void* x       = d_in[0];
    const void* lin0_w  = d_in[1];
    const void* lin0_b  = d_in[2];
    const void* conv0_w = d_in[3];
    const void* conv0_b = d_in[4];
    const void* lin1_w  = d_in[5];
    const void* lin1_b  = d_in[6];
    const void* conv1_w = d_in[7];
    const void* conv1_b = d_in[8];
    const void* linf_w  = d_in[9];
    const void* linf_b  = d_in[10];
    const int* consec   = (const int*)d_in[11];
    const int* cnc      = (const int*)d_in[12];
    const int* unc      = (const int*)d_in[13];

    int N = in_sizes[0] / 3;
    int U = in_sizes[13];

    float* ws    = (float*)d_ws;
    int*   flag  = (int*)d_ws;
    float* sums4  = ws + OFF_SUMS;
    float* gridA0 = ws + OFF_GA0;
    float* gridA1 = ws + OFF_GA1;
    float* conv1o = ws + OFF_C1O;
    float* conv0o = ws + OFF_C0O;
    float* w1t    = ws + OFF_W1T;
    float* Wc     = ws + OFF_WC;
    float* bvec   = ws + OFF_BVEC;
    bf16*  G      = (bf16*)(ws + OFF_G);

    // zero sums4 + gridA0 + gridA1 + conv1o (contiguous range)
    hipMemsetAsync((char*)d_ws + (size_t)OFF_SUMS * 4, 0,
                   (size_t)(OFF_C0O - OFF_SUMS) * 4, stream);

    k_probe<<<1, 256, 0, stream>>>(lin1_w, flag);
    k_convert<<<(120576 + 255) / 256, 256, 0, stream>>>(
        lin0_w, lin0_b, conv0_w, conv0_b, lin1_w, lin1_b, conv1_w, conv1_b,
        linf_w, linf_b, flag, ws);
    k_prep<<<1, 64, 0, stream>>>(ws, Wc, bvec);
    k_accum<<<(N + 255) / 256, 256, 0, stream>>>(x, consec, flag, sums4, N);
    k_scatter0<<<(U + 255) / 256, 256, 0, stream>>>(sums4, unc, gridA0, U);
    k_conv0<<<(64 * BVOXN + 255) / 256, 256, 0, stream>>>(gridA0, ws + OFF_W0,
                                                          ws + OFF_CB0, conv0o);
    k_scatter1<<<U, 64, 0, stream>>>(sums4, unc, conv0o, ws + OFF_L0W, ws + OFF_B0,
                                     gridA1);
    k_conv1<<<576, 256, 0, stream>>>(gridA1, w1t, conv1o);
    k_G<<<BVOXN, 64, 0, stream>>>(conv0o, conv1o, ws + OFF_L1W, ws + OFF_CB1, G);
    long long tot = (long long)N * 64;
    k_out<<<(int)((tot + 255) / 256), 256, 0, stream>>>(x, cnc, Wc, bvec, G, flag,
                                                        d_out, N);
}

// Round 3
// 773.211 us; speedup vs baseline: 1.1954x; 1.1954x over previous
//
#include <hip/hip_runtime.h>
#include <hip/hip_bf16.h>
#include <stdint.h>

typedef __hip_bfloat16 bf16;

#define BVOXN 23328   // B * 729, B = 32 (fixed by setup_inputs)

__device__ __forceinline__ float b2f(bf16 v) { return __bfloat162float(v); }

// ---- workspace layout (float offsets) -------------------------------------
#define OFF_L0W   64        // 192    lin0_w f32
#define OFF_B0    256       // 64     lin0_b
#define OFF_W0    320       // 5184   conv0_w transposed [i][tap][o]
#define OFF_CB0   5504      // 64     conv0_b
#define OFF_L1W   5568      // 4096   lin1_w
#define OFF_B1    9664      // 64     lin1_b
#define OFF_W1T   9728      // 110592 conv1_w transposed [i][tap][o]
#define OFF_CB1   120320    // 64     conv1_b
#define OFF_LFW   120384    // 192    linf_w
#define OFF_BF    120576    // 64     linf_b
#define OFF_SUMS  120640    // 93312  u64[46656]: packed per-cluster sums (zeroed)
#define OFF_GA0   213952    // 69984  conv0 input grid f32 (zeroed)
#define OFF_GA1   283936    // 746496 slots = bf16[1492992] conv1 input (zeroed)
#define OFF_C1A   1030432   // 1492992 conv1 partial (i 0..31), plain stores
#define OFF_C1B   2523424   // 1492992 conv1 partial (i 32..63)
#define OFF_C0O   4016416   // 746496 slots = bf16[1492992] conv0 out
#define OFF_WC    4762912   // 192    folded point matrix
#define OFF_BVEC  4763104   // 64     folded bias
#define OFF_G     4763168   // 746496 slots = bf16[1492992] voxel table G
// end = 5509664 f32 = 22.04 MB (same footprint as round-2 proven)

// fixed-point packing for cluster sums: e = round(v*2^20) + 2^23 (always >0)
#define FP_SCALE 1048576.0f
#define FP_BIAS  8388608

// ---------------------------------------------------------------------------
// Decide whether float inputs are f32 (flag=1) or bf16 (flag=0).
__global__ void k_probe(const void* lin1_w, int* flag) {
    __shared__ int cnt[256];
    int t = threadIdx.x;
    const bf16* p = (const bf16*)lin1_w;
    int c = 0;
    for (int j = t; j < 2048; j += 256) {
        float v = b2f(p[2 * j]);
        if (!(v == v) || fabsf(v) > 64.0f || (v != 0.0f && fabsf(v) < 1e-20f)) c++;
    }
    cnt[t] = c;
    __syncthreads();
    for (int s = 128; s > 0; s >>= 1) {
        if (t < s) cnt[t] += cnt[t + s];
        __syncthreads();
    }
    if (t == 0) *flag = (cnt[0] > 100) ? 1 : 0;
}

__device__ __forceinline__ float ldf(const void* p, int j, int isf) {
    return isf ? ((const float*)p)[j] : b2f(((const bf16*)p)[j]);
}

// Convert all 10 weight arrays into canonical f32 ws copies (convs transposed).
__global__ void k_convert(const void* l0w, const void* l0b, const void* w0,
                          const void* cb0, const void* l1w, const void* l1b,
                          const void* w1, const void* cb1, const void* lfw,
                          const void* lfb, const int* flag, float* ws) {
    int t = blockIdx.x * 256 + threadIdx.x;
    if (t >= 120576) return;
    int isf = *flag;
    const void* src;
    int j;
    float* dst;
    if (t < 192)        { src = l0w; j = t;          dst = ws + OFF_L0W + j; }
    else if (t < 256)   { src = l0b; j = t - 192;    dst = ws + OFF_B0  + j; }
    else if (t < 5440)  {
        j = t - 256;                        // conv0_w [o][i][tap] -> [i][tap][o]
        int o = j / 81, r = j % 81, i = r / 27, tap = r % 27;
        src = w0;
        dst = ws + OFF_W0 + (i * 27 + tap) * 64 + o;
    }
    else if (t < 5504)  { src = cb0; j = t - 5440;   dst = ws + OFF_CB0 + j; }
    else if (t < 9600)  { src = l1w; j = t - 5504;   dst = ws + OFF_L1W + j; }
    else if (t < 9664)  { src = l1b; j = t - 9600;   dst = ws + OFF_B1  + j; }
    else if (t < 120256) {
        j = t - 9664;                       // conv1_w [o][i][tap] -> [i][tap][o]
        int o = j / 1728, r = j % 1728, i = r / 27, tap = r % 27;
        src = w1;
        dst = ws + OFF_W1T + (i * 27 + tap) * 64 + o;
    }
    else if (t < 120320) { src = cb1; j = t - 120256; dst = ws + OFF_CB1 + j; }
    else if (t < 120512) { src = lfw; j = t - 120320; dst = ws + OFF_LFW + j; }
    else                 { src = lfb; j = t - 120512; dst = ws + OFF_BF  + j; }
    *dst = ldf(src, j, isf);
}

// Fold: Wc = lin0_w@lin1_w + linf_w [3,64]; bvec = lin0_b@lin1_w + lin1_b + linf_b
__global__ void k_prep(const float* ws, float* Wc, float* bvec) {
    const float* l0w = ws + OFF_L0W;
    const float* l0b = ws + OFF_B0;
    const float* l1w = ws + OFF_L1W;
    const float* l1b = ws + OFF_B1;
    const float* lfw = ws + OFF_LFW;
    const float* lfb = ws + OFF_BF;
    int c = threadIdx.x;
    float bv = l1b[c] + lfb[c];
    for (int k = 0; k < 64; ++k) bv += l0b[k] * l1w[k * 64 + c];
    bvec[c] = bv;
    for (int r = 0; r < 3; ++r) {
        float wv = lfw[r * 64 + c];
        for (int k = 0; k < 64; ++k) wv += l0w[r * 64 + k] * l1w[k * 64 + c];
        Wc[r * 64 + c] = wv;
    }
}

// Per-cluster sums of x (3 ch) + counts: 2 packed u64 atomics per point.
// word0: [ch0 | ch1] fixed-point; word1: [count | ch2].
__global__ void k_accum(const void* x, const int* consec, const int* flag,
                        unsigned long long* sums8, int N) {
    int i = blockIdx.x * 256 + threadIdx.x;
    if (i >= N) return;
    int isf = *flag;
    int u = consec[i];
    float v0 = ldf(x, 3 * i + 0, isf);
    float v1 = ldf(x, 3 * i + 1, isf);
    float v2 = ldf(x, 3 * i + 2, isf);
    unsigned e0 = (unsigned)(__float2int_rn(v0 * FP_SCALE) + FP_BIAS);
    unsigned e1 = (unsigned)(__float2int_rn(v1 * FP_SCALE) + FP_BIAS);
    unsigned e2 = (unsigned)(__float2int_rn(v2 * FP_SCALE) + FP_BIAS);
    atomicAdd(&sums8[2 * u + 0], ((unsigned long long)e0 << 32) | e1);
    atomicAdd(&sums8[2 * u + 1], (1ull << 32) | e2);
}

__device__ __forceinline__ void decode_mean(const unsigned long long* sums8, int u,
                                            float& m0, float& m1, float& m2) {
    unsigned long long S1 = sums8[2 * u + 0];
    unsigned long long S2 = sums8[2 * u + 1];
    double n = (double)(unsigned)(S2 >> 32);
    double k = 1.0 / (1048576.0 * n);
    double nb = n * 8388608.0;
    m0 = (float)(((double)(unsigned)(S1 >> 32) - nb) * k);
    m1 = (float)(((double)(unsigned)(S1 & 0xffffffffu) - nb) * k);
    m2 = (float)(((double)(unsigned)(S2 & 0xffffffffu) - nb) * k);
}

// Scatter means into conv0 input grid (flat [3, BVOXN] raw-viewed as (B,3,9,9,9))
__global__ void k_scatter0(const unsigned long long* sums8, const int* unc,
                           float* gridA0, int U) {
    int u = blockIdx.x * 256 + threadIdx.x;
    if (u >= U) return;
    int v = unc[u];
    float m0, m1, m2;
    decode_mean(sums8, u, m0, m1, m2);
    gridA0[0 * BVOXN + v] = m0;
    gridA0[1 * BVOXN + v] = m1;
    gridA0[2 * BVOXN + v] = m2;
}

// conv0: (B,3,9,9,9)->(B,64,9,9,9), 3x3x3 pad 1, + bias. LDS padded slab, no
// bounds checks in inner loop. Block=(b,d); thread: 8 o x 3 hw.
__global__ __launch_bounds__(256) void k_conv0s(const float* gridA0, const float* w0t,
                                                const float* cb0, bf16* conv0o) {
    __shared__ float slab[3 * 363];
    int b = blockIdx.x / 9, d = blockIdx.x % 9;
    int t = threadIdx.x;
    for (int s = t; s < 3 * 363; s += 256) {
        int i = s / 363, rr = s % 363;
        int zz = rr / 121, p = rr % 121;
        int ph = p / 11, pw = p % 11;
        int z = d + zz - 1, hh = ph - 1, ww = pw - 1;
        float v = 0.0f;
        if ((unsigned)z < 9u && (unsigned)hh < 9u && (unsigned)ww < 9u)
            v = gridA0[b * 2187 + i * 729 + z * 81 + hh * 9 + ww];
        slab[s] = v;
    }
    __syncthreads();

    int og = t >> 5, l = t & 31;
    int hw[3], hj[3], wj[3];
    bool valid[3];
    #pragma unroll
    for (int j = 0; j < 3; ++j) {
        int q = l + 32 * j;
        valid[j] = q < 81;
        int qc = q < 81 ? q : 80;
        hw[j] = q; hj[j] = qc / 9; wj[j] = qc % 9;
    }
    float acc[8][3];
    #pragma unroll
    for (int oj = 0; oj < 8; ++oj) {
        float bv = cb0[og * 8 + oj];
        acc[oj][0] = bv; acc[oj][1] = bv; acc[oj][2] = bv;
    }

    for (int i = 0; i < 3; ++i) {
        const float* sb = slab + i * 363;
        const float* wb = w0t + (i * 27) * 64 + og * 8;
        for (int kd = 0; kd < 3; ++kd)
            for (int kh = 0; kh < 3; ++kh) {
                int ib0 = kd * 121 + (hj[0] + kh) * 11 + wj[0];
                int ib1 = kd * 121 + (hj[1] + kh) * 11 + wj[1];
                int ib2 = kd * 121 + (hj[2] + kh) * 11 + wj[2];
                #pragma unroll
                for (int kw = 0; kw < 3; ++kw) {
                    int tap = kd * 9 + kh * 3 + kw;
                    const float4* w4 = reinterpret_cast<const float4*>(wb + tap * 64);
                    float4 wA = w4[0];
                    float4 wB = w4[1];
                    float in0 = sb[ib0 + kw];
                    float in1 = sb[ib1 + kw];
                    float in2 = sb[ib2 + kw];
                    acc[0][0] += wA.x * in0; acc[0][1] += wA.x * in1; acc[0][2] += wA.x * in2;
                    acc[1][0] += wA.y * in0; acc[1][1] += wA.y * in1; acc[1][2] += wA.y * in2;
                    acc[2][0] += wA.z * in0; acc[2][1] += wA.z * in1; acc[2][2] += wA.z * in2;
                    acc[3][0] += wA.w * in0; acc[3][1] += wA.w * in1; acc[3][2] += wA.w * in2;
                    acc[4][0] += wB.x * in0; acc[4][1] += wB.x * in1; acc[4][2] += wB.x * in2;
                    acc[5][0] += wB.y * in0; acc[5][1] += wB.y * in1; acc[5][2] += wB.y * in2;
                    acc[6][0] += wB.z * in0; acc[6][1] += wB.z * in1; acc[6][2] += wB.z * in2;
                    acc[7][0] += wB.w * in0; acc[7][1] += wB.w * in1; acc[7][2] += wB.w * in2;
                }
            }
    }

    #pragma unroll
    for (int oj = 0; oj < 8; ++oj) {
        int o = og * 8 + oj;
        #pragma unroll
        for (int j = 0; j < 3; ++j)
            if (valid[j])
                conv0o[b * 46656 + o * 729 + d * 81 + hw[j]] =
                    __float2bfloat16(acc[oj][j]);
    }
}

// conv1 input grid (bf16): gridA1(c,v) = mean_x[u]@lin0_w[:,c]+lin0_b[c]+conv0o(c,v)
__global__ void k_scatter1(const unsigned long long* sums8, const int* unc,
                           const bf16* conv0o, const float* l0w, const float* l0b,
                           bf16* gridA1) {
    int u = blockIdx.x;
    int c = threadIdx.x;
    int v = unc[u];
    float m0, m1, m2;
    decode_mean(sums8, u, m0, m1, m2);
    float val = l0b[c] + m0 * l0w[c] + m1 * l0w[64 + c] + m2 * l0w[128 + c] +
                b2f(conv0o[c * BVOXN + v]);
    gridA1[c * BVOXN + v] = __float2bfloat16(val);
}

// conv1: (B,64,9,9,9)->(B,64,9,9,9), 3x3x3 pad 1. Block=(b,d,i-half).
// No atomics: i-half 0 -> outA, i-half 1 -> outB (summed in k_G).
__global__ __launch_bounds__(256) void k_conv1(const bf16* gridA1, const float* w1t,
                                               float* outA, float* outB) {
    __shared__ float slab[32 * 363];
    int blk = blockIdx.x;
    int ih = blk & 1;
    int t2 = blk >> 1;
    int b = t2 / 9, d = t2 % 9;
    int t = threadIdx.x;

    for (int s = t; s < 32 * 363; s += 256) {
        int i = s / 363, rr = s % 363;
        int zz = rr / 121, p = rr % 121;
        int ph = p / 11, pw = p % 11;
        int z = d + zz - 1, hh = ph - 1, ww = pw - 1;
        float v = 0.0f;
        if ((unsigned)z < 9u && (unsigned)hh < 9u && (unsigned)ww < 9u)
            v = b2f(gridA1[b * 46656 + (ih * 32 + i) * 729 + z * 81 + hh * 9 + ww]);
        slab[s] = v;
    }
    __syncthreads();

    int og = t >> 5, l = t & 31;
    int hw[3], hj[3], wj[3];
    bool valid[3];
    #pragma unroll
    for (int j = 0; j < 3; ++j) {
        int q = l + 32 * j;
        valid[j] = q < 81;
        int qc = q < 81 ? q : 80;
        hw[j] = q; hj[j] = qc / 9; wj[j] = qc % 9;
    }
    float acc[8][3];
    #pragma unroll
    for (int a = 0; a < 8; ++a)
        #pragma unroll
        for (int j = 0; j < 3; ++j) acc[a][j] = 0.0f;

    for (int i = 0; i < 32; ++i) {
        const float* sb = slab + i * 363;
        const float* wb = w1t + ((ih * 32 + i) * 27) * 64 + og * 8;
        for (int kd = 0; kd < 3; ++kd)
            for (int kh = 0; kh < 3; ++kh) {
                int ib0 = kd * 121 + (hj[0] + kh) * 11 + wj[0];
                int ib1 = kd * 121 + (hj[1] + kh) * 11 + wj[1];
                int ib2 = kd * 121 + (hj[2] + kh) * 11 + wj[2];
                #pragma unroll
                for (int kw = 0; kw < 3; ++kw) {
                    int tap = kd * 9 + kh * 3 + kw;
                    const float4* w4 = reinterpret_cast<const float4*>(wb + tap * 64);
                    float4 wA = w4[0];
                    float4 wB = w4[1];
                    float in0 = sb[ib0 + kw];
                    float in1 = sb[ib1 + kw];
                    float in2 = sb[ib2 + kw];
                    acc[0][0] += wA.x * in0; acc[0][1] += wA.x * in1; acc[0][2] += wA.x * in2;
                    acc[1][0] += wA.y * in0; acc[1][1] += wA.y * in1; acc[1][2] += wA.y * in2;
                    acc[2][0] += wA.z * in0; acc[2][1] += wA.z * in1; acc[2][2] += wA.z * in2;
                    acc[3][0] += wA.w * in0; acc[3][1] += wA.w * in1; acc[3][2] += wA.w * in2;
                    acc[4][0] += wB.x * in0; acc[4][1] += wB.x * in1; acc[4][2] += wB.x * in2;
                    acc[5][0] += wB.y * in0; acc[5][1] += wB.y * in1; acc[5][2] += wB.y * in2;
                    acc[6][0] += wB.z * in0; acc[6][1] += wB.z * in1; acc[6][2] += wB.z * in2;
                    acc[7][0] += wB.w * in0; acc[7][1] += wB.w * in1; acc[7][2] += wB.w * in2;
                }
            }
    }

    float* out = ih ? outB : outA;
    #pragma unroll
    for (int oj = 0; oj < 8; ++oj) {
        int o = og * 8 + oj;
        #pragma unroll
        for (int j = 0; j < 3; ++j)
            if (valid[j])
                out[b * 46656 + o * 729 + d * 81 + hw[j]] = acc[oj][j];
    }
}

// G(v,c) = sum_k conv0o(k,v)*lin1_w[k][c] + conv1A(c,v)+conv1B(c,v) + conv1_b
__global__ void k_G(const bf16* conv0o, const float* c1A, const float* c1B,
                    const float* l1w, const float* cb1, bf16* G) {
    int v = blockIdx.x;
    int c = threadIdx.x;
    float a = 0.0f;
    for (int k = 0; k < 64; ++k)
        a += b2f(conv0o[k * BVOXN + v]) * l1w[k * 64 + c];
    int p = c * BVOXN + v;
    a += c1A[p] + c1B[p] + cb1[(p / 729) & 63];
    G[v * 64 + c] = __float2bfloat16(a);
}

// out[i][c] = x[i]@Wc[:,c] + bvec[c] + G[cnc[i]][c]
__global__ __launch_bounds__(256) void k_out(const void* x, const int* cnc,
                                             const float* Wc, const float* bvec,
                                             const bf16* G, const int* flag,
                                             void* out, int N) {
    int t = blockIdx.x * 256 + threadIdx.x;
    int i = t >> 6;
    int c = t & 63;
    if (i >= N) return;
    int isf = *flag;
    int v = cnc[i];
    float x0 = ldf(x, 3 * i + 0, isf);
    float x1 = ldf(x, 3 * i + 1, isf);
    float x2 = ldf(x, 3 * i + 2, isf);
    float r = bvec[c] + x0 * Wc[c] + x1 * Wc[64 + c] + x2 * Wc[128 + c] +
              b2f(G[v * 64 + c]);
    size_t oi = (size_t)i * 64 + c;
    if (isf) ((float*)out)[oi] = r;
    else ((bf16*)out)[oi] = __float2bfloat16(r);
}

// ---------------------------------------------------------------------------
extern "C" void kernel_launch(void* const* d_in, const int* in_sizes, int n_in,
                              void* d_out, int out_size, void* d_ws, size_t ws_size,
                              hipStream_t stream) {
    const void* x       = d_in[0];
    const void* lin0_w  = d_in[1];
    const void* lin0_b  = d_in[2];
    const void* conv0_w = d_in[3];
    const void* conv0_b = d_in[4];
    const void* lin1_w  = d_in[5];
    const void* lin1_b  = d_in[6];
    const void* conv1_w = d_in[7];
    const void* conv1_b = d_in[8];
    const void* linf_w  = d_in[9];
    const void* linf_b  = d_in[10];
    const int* consec   = (const int*)d_in[11];
    const int* cnc      = (const int*)d_in[12];
    const int* unc      = (const int*)d_in[13];

    int N = in_sizes[0] / 3;
    int U = in_sizes[13];

    float* ws   = (float*)d_ws;
    int*   flag = (int*)d_ws;
    unsigned long long* sums8 = (unsigned long long*)(ws + OFF_SUMS);
    float* gridA0 = ws + OFF_GA0;
    bf16*  gridA1 = (bf16*)(ws + OFF_GA1);
    float* c1A    = ws + OFF_C1A;
    float* c1B    = ws + OFF_C1B;
    bf16*  conv0o = (bf16*)(ws + OFF_C0O);
    float* Wc     = ws + OFF_WC;
    float* bvec   = ws + OFF_BVEC;
    bf16*  G      = (bf16*)(ws + OFF_G);

    // zero sums8 + gridA0 + gridA1 (contiguous range)
    hipMemsetAsync((char*)d_ws + (size_t)OFF_SUMS * 4, 0,
                   (size_t)(OFF_C1A - OFF_SUMS) * 4, stream);

    k_probe<<<1, 256, 0, stream>>>(lin1_w, flag);
    k_convert<<<(120576 + 255) / 256, 256, 0, stream>>>(
        lin0_w, lin0_b, conv0_w, conv0_b, lin1_w, lin1_b, conv1_w, conv1_b,
        linf_w, linf_b, flag, ws);
    k_prep<<<1, 64, 0, stream>>>(ws, Wc, bvec);
    k_accum<<<(N + 255) / 256, 256, 0, stream>>>(x, consec, flag, sums8, N);
    k_scatter0<<<(U + 255) / 256, 256, 0, stream>>>(sums8, unc, gridA0, U);
    k_conv0s<<<288, 256, 0, stream>>>(gridA0, ws + OFF_W0, ws + OFF_CB0, conv0o);
    k_scatter1<<<U, 64, 0, stream>>>(sums8, unc, conv0o, ws + OFF_L0W, ws + OFF_B0,
                                     gridA1);
    k_conv1<<<576, 256, 0, stream>>>(gridA1, ws + OFF_W1T, c1A, c1B);
    k_G<<<BVOXN, 64, 0, stream>>>(conv0o, c1A, c1B, ws + OFF_L1W, ws + OFF_CB1, G);
    long long tot = (long long)N * 64;
    k_out<<<(int)((tot + 255) / 256), 256, 0, stream>>>(x, cnc, Wc, bvec, G, flag,
                                                        d_out, N);
}